// Round 2
// baseline (2631.872 us; speedup 1.0000x reference)
//
#include <hip/hip_runtime.h>
#include <float.h>
#include <math.h>
#include <stdint.h>

#define TOKENS 8192
#define DIM    4096

typedef __attribute__((address_space(3))) unsigned int lds_uint;
typedef const __attribute__((address_space(1))) unsigned int glob_uint;

__device__ __forceinline__ void async_copy16(const float* g, float* l) {
    // one instr: 64 lanes x 16 B -> LDS at (uniform base + lane*16)
    __builtin_amdgcn_global_load_lds((glob_uint*)g, (lds_uint*)l, 16, 0, 0);
}

// ---------------------------------------------------------------------------
// Prep: WT4[dblk][e][dj] = W[e][dblk*4+dj]  (dblk = d/4), 1 MB in d_ws.
// Main kernel then loads W[e][d0..d0+3] as one dwordx4 with imm offset e*16.
// ---------------------------------------------------------------------------
__global__ __launch_bounds__(256) void prep_w_kernel(
    const float* __restrict__ W, float* __restrict__ WT4) {
    int f4 = blockIdx.x * 256 + threadIdx.x;      // 0..65535
    int dblk = f4 >> 6, e = f4 & 63;
    const float* src = W + (size_t)e * DIM + dblk * 4;
    float4 v;
    v.x = src[0]; v.y = src[1]; v.z = src[2]; v.w = src[3];
    *(float4*)(WT4 + (size_t)f4 * 4) = v;         // coalesced writes
}

// ---------------------------------------------------------------------------
// Main: lane = (t:16 tokens, eg:4 expert-groups), acc[16] experts per lane.
// 4 waves = D-quarters (1024 d each). 512 blocks x 16 tokens.
// x: global_load_lds double-buffered, pre-swizzled source, counted vmcnt.
// W: VGPR dwordx4 loads, uniform per eg-quad, L1-hot.
// ---------------------------------------------------------------------------
__global__ __launch_bounds__(256, 2) void topkgate_kernel(
    const float* __restrict__ x,
    const float* __restrict__ WT4,
    float* __restrict__ out) {

    __shared__ float tiles[4][2][512];    // per-wave double-buffered x tile [16 t][32 d]
    __shared__ float red[4][64][16];      // cross-wave reduction buffer

    const int tid  = threadIdx.x;
    const int wq   = tid >> 6;            // D-quarter
    const int lane = tid & 63;
    const int t    = lane & 15;           // token within block
    const int eg   = lane >> 4;           // expert group (16 experts each)
    const int rho  = t >> 1;              // LDS read swizzle key
    const int tok0 = blockIdx.x * 16;

    // per-lane pre-swizzled global source addresses for the two staging instrs:
    // LDS slot s = t*8 + (k ^ (t>>1)) holds x[t][dc + k*4 .. +3]  (conflict-free reads)
    const int s0 = lane,      st0 = s0 >> 3, sk0 = (s0 & 7) ^ (st0 >> 1);
    const int s1 = 64 + lane, st1 = s1 >> 3, sk1 = (s1 & 7) ^ (st1 >> 1);
    const float* g0 = x + (size_t)(tok0 + st0) * DIM + wq * 1024 + sk0 * 4;
    const float* g1 = x + (size_t)(tok0 + st1) * DIM + wq * 1024 + sk1 * 4;

    float acc[16];
    #pragma unroll
    for (int j = 0; j < 16; ++j) acc[j] = 0.f;

    // prologue: prefetch tiles for dc=0 (buf0) and dc=32 (buf1)
    async_copy16(g0, &tiles[wq][0][0]);
    async_copy16(g1, &tiles[wq][0][256]);
    g0 += 32; g1 += 32;
    async_copy16(g0, &tiles[wq][1][0]);
    async_copy16(g1, &tiles[wq][1][256]);
    g0 += 32; g1 += 32;

    for (int dc = 0; dc < 1024; dc += 32) {
        const int buf = (dc >> 5) & 1;
        // counted wait: leave the next tile's 2 loads in flight (drain at the tail)
        if (dc + 64 < 1024) asm volatile("s_waitcnt vmcnt(2)" ::: "memory");
        else                asm volatile("s_waitcnt vmcnt(0)" ::: "memory");
        __builtin_amdgcn_sched_barrier(0);

        const float* wp = WT4 + ((size_t)(wq * 256 + (dc >> 2)) << 8) + eg * 64;
        const float* xt = &tiles[wq][buf][t * 32];

        #pragma unroll
        for (int k = 0; k < 8; ++k) {             // 8 chunks of 4 d
            const float4 xv = *(const float4*)(xt + ((k ^ rho) << 2));
            const float* wk = wp + (size_t)k * 256;
            #pragma unroll
            for (int j = 0; j < 16; ++j) {        // 16 experts per lane
                float4 w = *(const float4*)(wk + j * 4);
                acc[j] = fmaf(xv.x, w.x, acc[j]);
                acc[j] = fmaf(xv.y, w.y, acc[j]);
                acc[j] = fmaf(xv.z, w.z, acc[j]);
                acc[j] = fmaf(xv.w, w.w, acc[j]);
            }
        }

        // prefetch tile dc+64 into the buffer we just finished reading
        if (dc + 64 < 1024) {
            async_copy16(g0, &tiles[wq][buf][0]);
            async_copy16(g1, &tiles[wq][buf][256]);
            g0 += 32; g1 += 32;
        }
    }

    // ---- cross-wave (D-quarter) reduction ----
    #pragma unroll
    for (int j = 0; j < 16; ++j) red[wq][lane][j] = acc[j];
    __syncthreads();

    if (wq == 0) {
        // per-lane top-2 over its 16 experts (ascending e -> strict > keeps smaller idx)
        float v1 = -FLT_MAX, v2 = -FLT_MAX;
        int   i1 = 0, i2 = 0;
        #pragma unroll
        for (int j = 0; j < 16; ++j) {
            float v = red[0][lane][j] + red[1][lane][j]
                    + red[2][lane][j] + red[3][lane][j];
            int e = eg * 16 + j;
            if (v > v1)      { v2 = v1; i2 = i1; v1 = v; i1 = e; }
            else if (v > v2) { v2 = v;  i2 = e; }
        }
        // merge the 4 eg-groups (lanes t, t+16, t+32, t+48): xor 16 then xor 32
        #pragma unroll
        for (int off = 16; off <= 32; off <<= 1) {
            float ov1 = __shfl_xor(v1, off);
            int   oi1 = __shfl_xor(i1, off);
            float ov2 = __shfl_xor(v2, off);
            int   oi2 = __shfl_xor(i2, off);
            bool obeats = (ov1 > v1) || (ov1 == v1 && oi1 < i1);
            float nv1 = obeats ? ov1 : v1;  int ni1 = obeats ? oi1 : i1;
            float ca  = obeats ? v1  : ov1; int cia = obeats ? i1  : oi1; // loser of #1s
            float cb  = obeats ? ov2 : v2;  int cib = obeats ? oi2 : i2;  // winner's #2
            bool bb = (cb > ca) || (cb == ca && cib < cia);
            v1 = nv1; i1 = ni1;
            v2 = bb ? cb : ca;
            i2 = bb ? cib : cia;
        }
        if (eg == 0) {
            // softmax cancels: g0 = 1/(1+exp(l2-l1)), l2<=l1 so no overflow
            float gtop = 1.0f / (1.0f + expf(v2 - v1));
            int gt = tok0 + t;
            out[gt]              = (float)i1;
            out[TOKENS + gt]     = (float)i2;
            out[2 * TOKENS + gt] = gtop;
            out[3 * TOKENS + gt] = 1.0f - gtop;
        }
    }
}

extern "C" void kernel_launch(void* const* d_in, const int* in_sizes, int n_in,
                              void* d_out, int out_size, void* d_ws, size_t ws_size,
                              hipStream_t stream) {
    const float* x = (const float*)d_in[0];   // [8192, 4096] fp32
    const float* W = (const float*)d_in[1];   // [64, 4096] fp32
    float* out = (float*)d_out;               // [4 * 8192] fp32
    float* WT4 = (float*)d_ws;                // [1024][64][4] fp32 (1 MB)

    prep_w_kernel<<<256, 256, 0, stream>>>(W, WT4);
    topkgate_kernel<<<512, 256, 0, stream>>>(x, WT4, out);
}

// Round 3
// 273.272 us; speedup vs baseline: 9.6310x; 9.6310x over previous
//
#include <hip/hip_runtime.h>
#include <float.h>
#include <math.h>

#define TOKENS 8192
#define DIM    4096
#define NEXP   64
#define TPB    8     // tokens per block

// ---------------------------------------------------------------------------
// Prep: WT4[dblk][e][0..3] = W[e][dblk*4 .. dblk*4+3]   (dblk = d/4; 1 MB).
// Main kernel reads one b128 per lane per dblk: WT4 + dblk*256 + lane*4
// -> 64 lanes x 16 B contiguous = 1 KB coalesced, L2-resident.
// ---------------------------------------------------------------------------
__global__ __launch_bounds__(256) void prep_w_kernel(
    const float* __restrict__ W, float* __restrict__ WT4) {
    int f = blockIdx.x * 256 + threadIdx.x;   // 65536 = dblk*64 + e
    int dblk = f >> 6, e = f & 63;
    const float* src = W + (size_t)e * DIM + dblk * 4;
    float4 v;
    v.x = src[0]; v.y = src[1]; v.z = src[2]; v.w = src[3];
    *(float4*)(WT4 + (size_t)f * 4) = v;
}

// ---------------------------------------------------------------------------
// Main: lane = expert (64 = wave width). Block = 8 tokens, 4 waves = D-quarters.
// x operands are WAVE-UNIFORM (no threadIdx in their address) -> scalar/broadcast
// loads; W is per-lane coalesced dwordx4. No LDS in the main loop.
// Grid 1024 blocks -> 4 blocks/CU, 16 waves/CU.
// ---------------------------------------------------------------------------
__global__ __launch_bounds__(256, 4) void topkgate_kernel(
    const float* __restrict__ x,
    const float* __restrict__ WT4,
    float* __restrict__ out) {

    __shared__ float red[4][TPB][64];         // 8 KB cross-wave reduction buffer

    const int tid  = threadIdx.x;
    const int wq   = tid >> 6;                // D-quarter (1024 d)
    const int lane = tid & 63;                // expert id
    const int tok0 = blockIdx.x * TPB;

    // wave-uniform x base (wq uniform within wave); per-lane W base
    const float* xbase = x + (size_t)tok0 * DIM + wq * 1024;
    const float* wbase = WT4 + ((size_t)(wq * 256) << 8) + lane * 4;

    float acc[TPB];
    #pragma unroll
    for (int t = 0; t < TPB; ++t) acc[t] = 0.f;

    for (int dc = 0; dc < 1024; dc += 16) {   // 16 d per step = 4 dblks
        const float* wp = wbase + ((size_t)(dc >> 2) << 8);
        float4 w0 = *(const float4*)(wp);
        float4 w1 = *(const float4*)(wp + 256);
        float4 w2 = *(const float4*)(wp + 512);
        float4 w3 = *(const float4*)(wp + 768);

        #pragma unroll
        for (int t = 0; t < TPB; ++t) {
            const float* xr = xbase + (size_t)t * DIM + dc;  // uniform address
            float4 a = *(const float4*)(xr);
            float4 b = *(const float4*)(xr + 4);
            float4 c = *(const float4*)(xr + 8);
            float4 d = *(const float4*)(xr + 12);
            float s = acc[t];
            s = fmaf(a.x, w0.x, s); s = fmaf(a.y, w0.y, s);
            s = fmaf(a.z, w0.z, s); s = fmaf(a.w, w0.w, s);
            s = fmaf(b.x, w1.x, s); s = fmaf(b.y, w1.y, s);
            s = fmaf(b.z, w1.z, s); s = fmaf(b.w, w1.w, s);
            s = fmaf(c.x, w2.x, s); s = fmaf(c.y, w2.y, s);
            s = fmaf(c.z, w2.z, s); s = fmaf(c.w, w2.w, s);
            s = fmaf(d.x, w3.x, s); s = fmaf(d.y, w3.y, s);
            s = fmaf(d.z, w3.z, s); s = fmaf(d.w, w3.w, s);
            acc[t] = s;
        }
    }

    // ---- cross-wave (D-quarter) reduction via LDS ----
    #pragma unroll
    for (int t = 0; t < TPB; ++t) red[wq][t][lane] = acc[t];
    __syncthreads();

    // ---- per-token top-2 + gates; wave wq handles tokens wq*2, wq*2+1 ----
    #pragma unroll
    for (int tt = 0; tt < 2; ++tt) {
        int t = wq * 2 + tt;
        float v = red[0][t][lane] + red[1][t][lane]
                + red[2][t][lane] + red[3][t][lane];     // logit[t][lane]

        // argmax #1 (tie-break: smaller index, matching jax.lax.top_k)
        float bv = v; int bi = lane;
        #pragma unroll
        for (int off = 32; off >= 1; off >>= 1) {
            float ov = __shfl_xor(bv, off);
            int   oi = __shfl_xor(bi, off);
            if (ov > bv || (ov == bv && oi < bi)) { bv = ov; bi = oi; }
        }
        // argmax #2 (exclude bi)
        float v2 = (lane == bi) ? -FLT_MAX : v;
        float bv2 = v2; int bi2 = lane;
        #pragma unroll
        for (int off = 32; off >= 1; off >>= 1) {
            float ov = __shfl_xor(bv2, off);
            int   oi = __shfl_xor(bi2, off);
            if (ov > bv2 || (ov == bv2 && oi < bi2)) { bv2 = ov; bi2 = oi; }
        }

        if (lane == 0) {
            // top-2 renormalized softmax cancels: g0 = 1/(1+exp(l1-l0))
            float g0 = 1.0f / (1.0f + expf(bv2 - bv));
            int gt = tok0 + t;
            out[gt]              = (float)bi;
            out[TOKENS + gt]     = (float)bi2;
            out[2 * TOKENS + gt] = g0;
            out[3 * TOKENS + gt] = 1.0f - g0;
        }
    }
}

extern "C" void kernel_launch(void* const* d_in, const int* in_sizes, int n_in,
                              void* d_out, int out_size, void* d_ws, size_t ws_size,
                              hipStream_t stream) {
    const float* x = (const float*)d_in[0];   // [8192, 4096] fp32
    const float* W = (const float*)d_in[1];   // [64, 4096] fp32
    float* out = (float*)d_out;               // [4 * 8192] fp32
    float* WT4 = (float*)d_ws;                // [1024][64][4] fp32 (1 MB)

    prep_w_kernel<<<256, 256, 0, stream>>>(W, WT4);
    topkgate_kernel<<<TOKENS / TPB, 256, 0, stream>>>(x, WT4, out);
}

// Round 4
// 69.267 us; speedup vs baseline: 37.9959x; 3.9452x over previous
//
#include <hip/hip_runtime.h>
#include <float.h>
#include <math.h>

#define TOKENS 8192
#define DIM    4096

typedef _Float16 v8h  __attribute__((ext_vector_type(8)));
typedef float    v4f  __attribute__((ext_vector_type(4)));

// ---------------------------------------------------------------------------
// Prep: build fp16 B-fragments of W (hi + lo*2048 split) in d_ws (1 MB).
// Layout: WF[chunk(128)][term(2)][et(4)][lane(64)][8 halfs]
//   fragment content: B[k][n] = W_term[e = et*16 + (lane&15)][k = chunk*32 + (lane>>4)*8 + j]
// Main kernel loads one fragment as a single coalesced b128 per lane.
// ---------------------------------------------------------------------------
__global__ __launch_bounds__(256) void prep_w_kernel(
    const float* __restrict__ W, _Float16* __restrict__ WF) {
    int n = blockIdx.x * 256 + threadIdx.x;   // 32768 threads
    int chunk = n >> 8;
    int et    = (n >> 6) & 3;
    int lane  = n & 63;
    int e  = et * 16 + (lane & 15);
    int k0 = chunk * 32 + (lane >> 4) * 8;
    const float* src = W + (size_t)e * DIM + k0;
    v8h h, l;
    #pragma unroll
    for (int j = 0; j < 8; ++j) {
        float w = src[j];
        _Float16 wh = (_Float16)w;                     // RTN
        h[j] = wh;
        l[j] = (_Float16)((w - (float)wh) * 2048.0f);  // residual, rescaled
    }
    // halves offset: chunk*4096 + term*2048 + et*512 + lane*8
    size_t base = (size_t)chunk * 4096 + (size_t)et * 512 + (size_t)lane * 8;
    *(v8h*)(WF + base)        = h;
    *(v8h*)(WF + base + 2048) = l;
}

// ---------------------------------------------------------------------------
// Main: 512 blocks x 256 threads. Block = 16 tokens; wave wq = K-quarter.
// Wave-private double-buffered x staging (reg-staged: global->VGPR early,
// ds_write late). XOR swizzle on 16B groups for conflict-free ds_read_b128.
// 3-term fp16-split MFMA: acc1 = xh*wh ; acc2 = xl'*wh + xh*wl' (scale 1/2048).
// ---------------------------------------------------------------------------
__global__ __launch_bounds__(256, 2) void topkgate_kernel(
    const float* __restrict__ x,
    const _Float16* __restrict__ WF,
    float* __restrict__ out) {

    __shared__ float tiles[4][2][1024];   // [wave][buf][16 tok x 64 d] (swizzled) = 32 KB
    __shared__ float red[4][16][64];      // partial logits, 16 KB

    const int tid  = threadIdx.x;
    const int wq   = tid >> 6;            // K-quarter (1024 d)
    const int lane = tid & 63;
    const int tok0 = blockIdx.x * 16;

    // ---- staging addressing: lane stages token i*4+(lane>>4), 16B-group lane&15 ----
    const int srow = lane >> 4;
    const int sgl  = lane & 15;
    const float* gsrc[4];
    int wofs[4];
    #pragma unroll
    for (int i = 0; i < 4; ++i) {
        int t = i * 4 + srow;
        gsrc[i] = x + (size_t)(tok0 + t) * DIM + wq * 1024 + sgl * 4;
        wofs[i] = t * 64 + ((sgl ^ (t & 7)) << 2);          // swizzled LDS float offset
    }

    // ---- A-fragment read offsets: lane reads token art, 8 consecutive k ----
    const int art = lane & 15;            // token row within tile
    const int akg = lane >> 4;            // k-group
    int rofs[2][2];
    #pragma unroll
    for (int c = 0; c < 2; ++c) {
        int g0 = c * 8 + akg * 2;         // logical 16B group of first 4 floats
        rofs[c][0] = art * 64 + (((g0    ) ^ (art & 7)) << 2);
        rofs[c][1] = art * 64 + (((g0 + 1) ^ (art & 7)) << 2);
    }

    v4f acc1[4], acc2[4];
    #pragma unroll
    for (int e4 = 0; e4 < 4; ++e4) {
        acc1[e4] = (v4f)0.0f;
        acc2[e4] = (v4f)0.0f;
    }

    float* buf0 = &tiles[wq][0][0];
    float* buf1 = &tiles[wq][1][0];

    // ---- prologue: stage step 0 ----
    {
        float4 stg[4];
        #pragma unroll
        for (int i = 0; i < 4; ++i) stg[i] = *(const float4*)(gsrc[i]);
        #pragma unroll
        for (int i = 0; i < 4; ++i) *(float4*)(buf0 + wofs[i]) = stg[i];
    }

    #pragma unroll 1
    for (int s = 0; s < 16; ++s) {        // 16 stage-steps of 64 d
        float* cur = (s & 1) ? buf1 : buf0;
        float* nxt = (s & 1) ? buf0 : buf1;

        // issue next step's global loads early (latency hides under MFMA)
        float4 st[4];
        if (s < 15) {
            #pragma unroll
            for (int i = 0; i < 4; ++i) st[i] = *(const float4*)(gsrc[i] + (s + 1) * 64);
        }

        #pragma unroll
        for (int c = 0; c < 2; ++c) {     // two K=32 chunks per step
            const int chunk = wq * 32 + s * 2 + c;
            const _Float16* wfc = WF + (size_t)chunk * 4096 + (size_t)lane * 8;
            v8h bh[4], bl[4];
            #pragma unroll
            for (int e4 = 0; e4 < 4; ++e4) {
                bh[e4] = *(const v8h*)(wfc + e4 * 512);
                bl[e4] = *(const v8h*)(wfc + 2048 + e4 * 512);
            }
            float4 a0 = *(const float4*)(cur + rofs[c][0]);
            float4 a1 = *(const float4*)(cur + rofs[c][1]);
            float av[8] = {a0.x, a0.y, a0.z, a0.w, a1.x, a1.y, a1.z, a1.w};
            v8h ah, al;
            #pragma unroll
            for (int j = 0; j < 8; ++j) {
                _Float16 h = (_Float16)av[j];
                ah[j] = h;
                al[j] = (_Float16)((av[j] - (float)h) * 2048.0f);
            }
            #pragma unroll
            for (int e4 = 0; e4 < 4; ++e4) {
                acc1[e4] = __builtin_amdgcn_mfma_f32_16x16x32_f16(ah, bh[e4], acc1[e4], 0, 0, 0);
                acc2[e4] = __builtin_amdgcn_mfma_f32_16x16x32_f16(al, bh[e4], acc2[e4], 0, 0, 0);
                acc2[e4] = __builtin_amdgcn_mfma_f32_16x16x32_f16(ah, bl[e4], acc2[e4], 0, 0, 0);
            }
        }

        // late LDS write of the prefetched tile (wave-private -> no barrier)
        if (s < 15) {
            #pragma unroll
            for (int i = 0; i < 4; ++i) *(float4*)(nxt + wofs[i]) = st[i];
        }
    }

    // ---- combine split terms, write partial logits ----
    // C/D layout: col(expert) = lane&15, row(token) = (lane>>4)*4 + reg
    const float inv2048 = 1.0f / 2048.0f;
    #pragma unroll
    for (int e4 = 0; e4 < 4; ++e4) {
        #pragma unroll
        for (int r = 0; r < 4; ++r) {
            red[wq][akg * 4 + r][e4 * 16 + art] = acc1[e4][r] + acc2[e4][r] * inv2048;
        }
    }
    __syncthreads();

    // ---- per-token top-2 + gates; wave wq handles tokens wq*4 .. wq*4+3 ----
    #pragma unroll
    for (int tt = 0; tt < 4; ++tt) {
        int t = wq * 4 + tt;
        float v = red[0][t][lane] + red[1][t][lane]
                + red[2][t][lane] + red[3][t][lane];     // logit[t][lane]

        // argmax #1 (tie-break: smaller index, matching jax.lax.top_k)
        float bv = v; int bi = lane;
        #pragma unroll
        for (int off = 32; off >= 1; off >>= 1) {
            float ov = __shfl_xor(bv, off);
            int   oi = __shfl_xor(bi, off);
            if (ov > bv || (ov == bv && oi < bi)) { bv = ov; bi = oi; }
        }
        // argmax #2 (exclude bi)
        float v2 = (lane == bi) ? -FLT_MAX : v;
        float bv2 = v2; int bi2 = lane;
        #pragma unroll
        for (int off = 32; off >= 1; off >>= 1) {
            float ov = __shfl_xor(bv2, off);
            int   oi = __shfl_xor(bi2, off);
            if (ov > bv2 || (ov == bv2 && oi < bi2)) { bv2 = ov; bi2 = oi; }
        }

        if (lane == 0) {
            // top-2 renormalized softmax cancels: g0 = 1/(1+exp(l1-l0))
            float g0 = 1.0f / (1.0f + expf(bv2 - bv));
            int gt = tok0 + t;
            out[gt]              = (float)bi;
            out[TOKENS + gt]     = (float)bi2;
            out[2 * TOKENS + gt] = g0;
            out[3 * TOKENS + gt] = 1.0f - g0;
        }
    }
}

extern "C" void kernel_launch(void* const* d_in, const int* in_sizes, int n_in,
                              void* d_out, int out_size, void* d_ws, size_t ws_size,
                              hipStream_t stream) {
    const float* x = (const float*)d_in[0];   // [8192, 4096] fp32
    const float* W = (const float*)d_in[1];   // [64, 4096] fp32
    float* out     = (float*)d_out;           // [4 * 8192] fp32
    _Float16* WF   = (_Float16*)d_ws;         // 1 MB fp16 W-fragments (hi/lo)

    prep_w_kernel<<<128, 256, 0, stream>>>(W, WF);
    topkgate_kernel<<<TOKENS / 16, 256, 0, stream>>>(x, WF, out);
}

// Round 5
// 54.545 us; speedup vs baseline: 48.2513x; 1.2699x over previous
//
#include <hip/hip_runtime.h>
#include <float.h>
#include <math.h>

#define TOKENS 8192
#define DIM    4096

typedef _Float16 v8h  __attribute__((ext_vector_type(8)));
typedef float    v4f  __attribute__((ext_vector_type(4)));

// ---------------------------------------------------------------------------
// Prep: fp16 hi/lo split B-fragments of W in d_ws (1 MB).
// WF[chunk(128)][term(2)][et(4)][lane(64)][8]:
//   B[k][n] with n = et*16 + (lane&15), k = chunk*32 + (lane>>4)*8 + j
// ---------------------------------------------------------------------------
__global__ __launch_bounds__(256) void prep_w_kernel(
    const float* __restrict__ W, _Float16* __restrict__ WF) {
    int n = blockIdx.x * 256 + threadIdx.x;   // 32768
    int chunk = n >> 8;
    int et    = (n >> 6) & 3;
    int lane  = n & 63;
    int e  = et * 16 + (lane & 15);
    int k0 = chunk * 32 + (lane >> 4) * 8;
    const float* src = W + (size_t)e * DIM + k0;
    v8h h, l;
    #pragma unroll
    for (int j = 0; j < 8; ++j) {
        float w = src[j];
        _Float16 wh = (_Float16)w;
        h[j] = wh;
        l[j] = (_Float16)((w - (float)wh) * 2048.0f);
    }
    size_t base = (size_t)chunk * 4096 + (size_t)et * 512 + (size_t)lane * 8;
    *(v8h*)(WF + base)        = h;
    *(v8h*)(WF + base + 2048) = l;
}

#define LOAD_CHUNK(cc, A0, A1, BH, BL) do {                                   \
    const float* ap_ = abase + (cc) * 32;                                     \
    A0 = *(const float4*)ap_;                                                 \
    A1 = *(const float4*)(ap_ + 4);                                           \
    const _Float16* wp_ = wbase + (size_t)(cc) * 4096;                        \
    _Pragma("unroll")                                                         \
    for (int e4_ = 0; e4_ < 4; ++e4_) {                                       \
        BH[e4_] = *(const v8h*)(wp_ + e4_ * 512);                             \
        BL[e4_] = *(const v8h*)(wp_ + 2048 + e4_ * 512);                      \
    }                                                                         \
} while (0)

#define COMPUTE_CHUNK(A0, A1, BH, BL) do {                                    \
    float av_[8] = {A0.x, A0.y, A0.z, A0.w, A1.x, A1.y, A1.z, A1.w};          \
    v8h ah_, al_;                                                             \
    _Pragma("unroll")                                                         \
    for (int j_ = 0; j_ < 8; ++j_) {                                          \
        _Float16 h_ = (_Float16)av_[j_];                                      \
        ah_[j_] = h_;                                                         \
        al_[j_] = (_Float16)((av_[j_] - (float)h_) * 2048.0f);                \
    }                                                                         \
    _Pragma("unroll")                                                         \
    for (int e4_ = 0; e4_ < 4; ++e4_)                                         \
        acc1[e4_] = __builtin_amdgcn_mfma_f32_16x16x32_f16(ah_, BH[e4_], acc1[e4_], 0, 0, 0); \
    _Pragma("unroll")                                                         \
    for (int e4_ = 0; e4_ < 4; ++e4_) {                                       \
        acc2[e4_] = __builtin_amdgcn_mfma_f32_16x16x32_f16(al_, BH[e4_], acc2[e4_], 0, 0, 0); \
        acc2[e4_] = __builtin_amdgcn_mfma_f32_16x16x32_f16(ah_, BL[e4_], acc2[e4_], 0, 0, 0); \
    }                                                                         \
} while (0)

// ---------------------------------------------------------------------------
// Logits: grid = 512*KB blocks x 256 thr (4 waves). Block = 16 tokens x
// (DIM/KB) d-range; wave wq = quarter of that = CH chunks of K=32.
// A direct from global (no LDS), B from L2-hot WF. Depth-1 two-set pipeline.
// KB==1: full top-2 in-kernel. KB==2: partial logits to P, reduce kernel after.
// ---------------------------------------------------------------------------
template <int KB>
__global__ __launch_bounds__(256) void logits_kernel(
    const float* __restrict__ x,
    const _Float16* __restrict__ WF,
    float* __restrict__ P,
    float* __restrict__ out) {

    constexpr int CH = 32 / KB;           // chunks per wave
    __shared__ float red[4][16][64];      // 16 KB

    const int tid  = threadIdx.x;
    const int wq   = tid >> 6;
    const int lane = tid & 63;
    const int kb   = (int)(blockIdx.x % KB);
    const int tok0 = (int)(blockIdx.x / KB) * 16;
    const int art  = lane & 15;           // token row in tile
    const int akg  = lane >> 4;           // k-group
    const int chunk0 = (kb * 4 + wq) * CH;

    const float*    abase = x  + (size_t)(tok0 + art) * DIM + chunk0 * 32 + akg * 8;
    const _Float16* wbase = WF + (size_t)chunk0 * 4096 + (size_t)lane * 8;

    v4f acc1[4], acc2[4];
    #pragma unroll
    for (int e4 = 0; e4 < 4; ++e4) { acc1[e4] = (v4f)0.0f; acc2[e4] = (v4f)0.0f; }

    float4 pa0, pa1; v8h pbh[4], pbl[4];  // set P
    float4 qa0, qa1; v8h qbh[4], qbl[4];  // set Q
    LOAD_CHUNK(0, pa0, pa1, pbh, pbl);

    #pragma unroll 1
    for (int c = 0; c < CH; c += 2) {
        LOAD_CHUNK(c + 1, qa0, qa1, qbh, qbl);
        COMPUTE_CHUNK(pa0, pa1, pbh, pbl);
        if (c + 2 < CH) LOAD_CHUNK(c + 2, pa0, pa1, pbh, pbl);
        COMPUTE_CHUNK(qa0, qa1, qbh, qbl);
    }

    // combine split terms -> red[wq][token][expert]
    const float inv2048 = 1.0f / 2048.0f;
    #pragma unroll
    for (int e4 = 0; e4 < 4; ++e4) {
        #pragma unroll
        for (int r = 0; r < 4; ++r) {
            red[wq][akg * 4 + r][e4 * 16 + art] = acc1[e4][r] + acc2[e4][r] * inv2048;
        }
    }
    __syncthreads();

    if (KB == 2) {
        // sum 4 wave-partials, write this block's K-half partial logits
        #pragma unroll
        for (int tt = 0; tt < 4; ++tt) {
            int t = wq * 4 + tt;
            float v = red[0][t][lane] + red[1][t][lane]
                    + red[2][t][lane] + red[3][t][lane];
            P[((size_t)kb * TOKENS + tok0 + t) * 64 + lane] = v;
        }
    } else {
        // single-pass: full top-2 + gates
        #pragma unroll
        for (int tt = 0; tt < 4; ++tt) {
            int t = wq * 4 + tt;
            float v = red[0][t][lane] + red[1][t][lane]
                    + red[2][t][lane] + red[3][t][lane];
            float bv = v; int bi = lane;
            #pragma unroll
            for (int off = 32; off >= 1; off >>= 1) {
                float ov = __shfl_xor(bv, off);
                int   oi = __shfl_xor(bi, off);
                if (ov > bv || (ov == bv && oi < bi)) { bv = ov; bi = oi; }
            }
            float v2 = (lane == bi) ? -FLT_MAX : v;
            float bv2 = v2; int bi2 = lane;
            #pragma unroll
            for (int off = 32; off >= 1; off >>= 1) {
                float ov = __shfl_xor(bv2, off);
                int   oi = __shfl_xor(bi2, off);
                if (ov > bv2 || (ov == bv2 && oi < bi2)) { bv2 = ov; bi2 = oi; }
            }
            if (lane == 0) {
                float g0 = 1.0f / (1.0f + expf(bv2 - bv));
                int gt = tok0 + t;
                out[gt]              = (float)bi;
                out[TOKENS + gt]     = (float)bi2;
                out[2 * TOKENS + gt] = g0;
                out[3 * TOKENS + gt] = 1.0f - g0;
            }
        }
    }
}

// ---------------------------------------------------------------------------
// Reduce (KB==2): logits = P[0]+P[1]; top-2 + gates. 512 blocks x 4 waves.
// ---------------------------------------------------------------------------
__global__ __launch_bounds__(256) void reduce_topk_kernel(
    const float* __restrict__ P, float* __restrict__ out) {
    const int wq   = threadIdx.x >> 6;
    const int lane = threadIdx.x & 63;
    #pragma unroll
    for (int tt = 0; tt < 4; ++tt) {
        int gt = blockIdx.x * 16 + wq * 4 + tt;
        float v = P[(size_t)gt * 64 + lane]
                + P[((size_t)TOKENS + gt) * 64 + lane];
        float bv = v; int bi = lane;
        #pragma unroll
        for (int off = 32; off >= 1; off >>= 1) {
            float ov = __shfl_xor(bv, off);
            int   oi = __shfl_xor(bi, off);
            if (ov > bv || (ov == bv && oi < bi)) { bv = ov; bi = oi; }
        }
        float v2 = (lane == bi) ? -FLT_MAX : v;
        float bv2 = v2; int bi2 = lane;
        #pragma unroll
        for (int off = 32; off >= 1; off >>= 1) {
            float ov = __shfl_xor(bv2, off);
            int   oi = __shfl_xor(bi2, off);
            if (ov > bv2 || (ov == bv2 && oi < bi2)) { bv2 = ov; bi2 = oi; }
        }
        if (lane == 0) {
            float g0 = 1.0f / (1.0f + expf(bv2 - bv));
            out[gt]              = (float)bi;
            out[TOKENS + gt]     = (float)bi2;
            out[2 * TOKENS + gt] = g0;
            out[3 * TOKENS + gt] = 1.0f - g0;
        }
    }
}

extern "C" void kernel_launch(void* const* d_in, const int* in_sizes, int n_in,
                              void* d_out, int out_size, void* d_ws, size_t ws_size,
                              hipStream_t stream) {
    const float* x = (const float*)d_in[0];   // [8192, 4096] fp32
    const float* W = (const float*)d_in[1];   // [64, 4096] fp32
    float* out     = (float*)d_out;           // [4 * 8192] fp32
    _Float16* WF   = (_Float16*)d_ws;         // 1 MB fragments
    float* P       = (float*)((char*)d_ws + (1 << 20));  // 4 MB partial logits

    prep_w_kernel<<<128, 256, 0, stream>>>(W, WF);

    const size_t need = (1 << 20) + (size_t)2 * TOKENS * 64 * sizeof(float);
    if (ws_size >= need) {
        logits_kernel<2><<<1024, 256, 0, stream>>>(x, WF, P, nullptr);
        reduce_topk_kernel<<<512, 256, 0, stream>>>(P, out);
    } else {
        logits_kernel<1><<<512, 256, 0, stream>>>(x, WF, nullptr, out);
    }
}

// Round 6
// 48.192 us; speedup vs baseline: 54.6118x; 1.1318x over previous
//
#include <hip/hip_runtime.h>
#include <float.h>
#include <math.h>

#define TOKENS 8192
#define DIM    4096

typedef _Float16 v8h  __attribute__((ext_vector_type(8)));
typedef float    v4f  __attribute__((ext_vector_type(4)));

// ---------------------------------------------------------------------------
// Prep: fp16 hi/lo split B-fragments of W in d_ws (1 MB).
// WF[chunk(128)][term(2)][et(4)][lane(64)][8]:
//   B[k][n] with n = et*16 + (lane&15), k = chunk*32 + (lane>>4)*8 + j
// ---------------------------------------------------------------------------
__global__ __launch_bounds__(256) void prep_w_kernel(
    const float* __restrict__ W, _Float16* __restrict__ WF) {
    int n = blockIdx.x * 256 + threadIdx.x;   // 32768
    int chunk = n >> 8;
    int et    = (n >> 6) & 3;
    int lane  = n & 63;
    int e  = et * 16 + (lane & 15);
    int k0 = chunk * 32 + (lane >> 4) * 8;
    const float* src = W + (size_t)e * DIM + k0;
    v8h h, l;
    #pragma unroll
    for (int j = 0; j < 8; ++j) {
        float w = src[j];
        _Float16 wh = (_Float16)w;
        h[j] = wh;
        l[j] = (_Float16)((w - (float)wh) * 2048.0f);
    }
    size_t base = (size_t)chunk * 4096 + (size_t)et * 512 + (size_t)lane * 8;
    *(v8h*)(WF + base)        = h;
    *(v8h*)(WF + base + 2048) = l;
}

// ---- pipelined load/compute helpers (all buffer names compile-time) --------
#define LOAD_A(Aa, Ab, cc) do {                                               \
    const float* ap_ = abase + (size_t)(cc) * 32;                             \
    Aa = *(const float4*)ap_;                                                 \
    Ab = *(const float4*)(ap_ + 4);                                           \
} while (0)

#define LOAD_B(BH, BL, cc) do {                                               \
    const _Float16* wp_ = wbase + (size_t)(cc) * 4096;                        \
    _Pragma("unroll")                                                         \
    for (int e_ = 0; e_ < 4; ++e_) {                                          \
        BH[e_] = *(const v8h*)(wp_ + e_ * 512);                               \
        BL[e_] = *(const v8h*)(wp_ + 2048 + e_ * 512);                        \
    }                                                                         \
} while (0)

#define COMP(Aa, Ab, BH, BL) do {                                             \
    float av_[8] = {Aa.x, Aa.y, Aa.z, Aa.w, Ab.x, Ab.y, Ab.z, Ab.w};          \
    v8h ah_, al_;                                                             \
    _Pragma("unroll")                                                         \
    for (int j_ = 0; j_ < 8; ++j_) {                                          \
        _Float16 h_ = (_Float16)av_[j_];                                      \
        ah_[j_] = h_;                                                         \
        al_[j_] = (_Float16)((av_[j_] - (float)h_) * 2048.0f);                \
    }                                                                         \
    _Pragma("unroll")                                                         \
    for (int e_ = 0; e_ < 4; ++e_)                                            \
        acc1[e_] = __builtin_amdgcn_mfma_f32_16x16x32_f16(ah_, BH[e_], acc1[e_], 0, 0, 0); \
    _Pragma("unroll")                                                         \
    for (int e_ = 0; e_ < 4; ++e_) {                                          \
        acc2[e_] = __builtin_amdgcn_mfma_f32_16x16x32_f16(al_, BH[e_], acc2[e_], 0, 0, 0); \
        acc2[e_] = __builtin_amdgcn_mfma_f32_16x16x32_f16(ah_, BL[e_], acc2[e_], 0, 0, 0); \
    }                                                                         \
} while (0)

// ---------------------------------------------------------------------------
// Single-pass logits + top-2. 512 blocks x 256 thr. Block = 16 tokens;
// wave wq = K-quarter (32 chunks of K=32). A from global depth-4,
// B from L2-hot WF depth-2. All buffers are named registers (no scratch).
// ---------------------------------------------------------------------------
__global__ __launch_bounds__(256, 2) void topkgate_kernel(
    const float* __restrict__ x,
    const _Float16* __restrict__ WF,
    float* __restrict__ out) {

    __shared__ float red[4][16][64];      // 16 KB

    const int tid  = threadIdx.x;
    const int wq   = tid >> 6;
    const int lane = tid & 63;
    const int tok0 = blockIdx.x * 16;
    const int art  = lane & 15;           // token row in tile
    const int akg  = lane >> 4;           // k-group
    const int chunk0 = wq * 32;

    const float*    abase = x  + (size_t)(tok0 + art) * DIM + chunk0 * 32 + akg * 8;
    const _Float16* wbase = WF + (size_t)chunk0 * 4096 + (size_t)lane * 8;

    v4f acc1[4], acc2[4];
    #pragma unroll
    for (int e4 = 0; e4 < 4; ++e4) { acc1[e4] = (v4f)0.0f; acc2[e4] = (v4f)0.0f; }

    float4 A0a, A0b, A1a, A1b, A2a, A2b, A3a, A3b;
    v8h B0h[4], B0l[4], B1h[4], B1l[4];

    // prologue: A depth 4, B depth 2
    LOAD_A(A0a, A0b, 0);
    LOAD_A(A1a, A1b, 1);
    LOAD_A(A2a, A2b, 2);
    LOAD_A(A3a, A3b, 3);
    LOAD_B(B0h, B0l, 0);
    LOAD_B(B1h, B1l, 1);

    #pragma unroll 1
    for (int c = 0; c <= 24; c += 4) {    // chunks 0..27
        COMP(A0a, A0b, B0h, B0l);  LOAD_A(A0a, A0b, c + 4);  LOAD_B(B0h, B0l, c + 2);
        COMP(A1a, A1b, B1h, B1l);  LOAD_A(A1a, A1b, c + 5);  LOAD_B(B1h, B1l, c + 3);
        COMP(A2a, A2b, B0h, B0l);  LOAD_A(A2a, A2b, c + 6);  LOAD_B(B0h, B0l, c + 4);
        COMP(A3a, A3b, B1h, B1l);  LOAD_A(A3a, A3b, c + 7);  LOAD_B(B1h, B1l, c + 5);
    }
    // epilogue: chunks 28..31 (A0..A3 hold 28..31; B0=28, B1=29)
    COMP(A0a, A0b, B0h, B0l);  LOAD_B(B0h, B0l, 30);
    COMP(A1a, A1b, B1h, B1l);  LOAD_B(B1h, B1l, 31);
    COMP(A2a, A2b, B0h, B0l);
    COMP(A3a, A3b, B1h, B1l);

    // combine split terms -> red[wq][token][expert]
    // C/D layout: col(expert frag) = lane&15, row = (lane>>4)*4 + reg
    const float inv2048 = 1.0f / 2048.0f;
    #pragma unroll
    for (int e4 = 0; e4 < 4; ++e4) {
        #pragma unroll
        for (int r = 0; r < 4; ++r) {
            red[wq][akg * 4 + r][e4 * 16 + art] = acc1[e4][r] + acc2[e4][r] * inv2048;
        }
    }
    __syncthreads();

    // per-token top-2 + gates; wave wq handles tokens wq*4 .. wq*4+3
    #pragma unroll
    for (int tt = 0; tt < 4; ++tt) {
        int t = wq * 4 + tt;
        float v = red[0][t][lane] + red[1][t][lane]
                + red[2][t][lane] + red[3][t][lane];     // logit[t][lane]

        float bv = v; int bi = lane;
        #pragma unroll
        for (int off = 32; off >= 1; off >>= 1) {
            float ov = __shfl_xor(bv, off);
            int   oi = __shfl_xor(bi, off);
            if (ov > bv || (ov == bv && oi < bi)) { bv = ov; bi = oi; }
        }
        float v2 = (lane == bi) ? -FLT_MAX : v;
        float bv2 = v2; int bi2 = lane;
        #pragma unroll
        for (int off = 32; off >= 1; off >>= 1) {
            float ov = __shfl_xor(bv2, off);
            int   oi = __shfl_xor(bi2, off);
            if (ov > bv2 || (ov == bv2 && oi < bi2)) { bv2 = ov; bi2 = oi; }
        }

        if (lane == 0) {
            // top-2 renormalized softmax cancels: g0 = 1/(1+exp(l1-l0))
            float g0 = 1.0f / (1.0f + expf(bv2 - bv));
            int gt = tok0 + t;
            out[gt]              = (float)bi;
            out[TOKENS + gt]     = (float)bi2;
            out[2 * TOKENS + gt] = g0;
            out[3 * TOKENS + gt] = 1.0f - g0;
        }
    }
}

extern "C" void kernel_launch(void* const* d_in, const int* in_sizes, int n_in,
                              void* d_out, int out_size, void* d_ws, size_t ws_size,
                              hipStream_t stream) {
    const float* x = (const float*)d_in[0];   // [8192, 4096] fp32
    const float* W = (const float*)d_in[1];   // [64, 4096] fp32
    float* out     = (float*)d_out;           // [4 * 8192] fp32
    _Float16* WF   = (_Float16*)d_ws;         // 1 MB fragments

    prep_w_kernel<<<128, 256, 0, stream>>>(W, WF);
    topkgate_kernel<<<TOKENS / 16, 256, 0, stream>>>(x, WF, out);
}

// Round 7
// 46.431 us; speedup vs baseline: 56.6835x; 1.0379x over previous
//
#include <hip/hip_runtime.h>
#include <float.h>
#include <math.h>

#define TOKENS 8192
#define DIM    4096

typedef _Float16 v8h  __attribute__((ext_vector_type(8)));
typedef float    v4f  __attribute__((ext_vector_type(4)));

// ---------------------------------------------------------------------------
// Prep: fp16 hi/lo split B-fragments of W in d_ws (1 MB).
// WF[chunk(128)][term(2)][et(4)][lane(64)][8]:
//   B[k][n] with n = et*16 + (lane&15), k = chunk*32 + (lane>>4)*8 + j
// ---------------------------------------------------------------------------
__global__ __launch_bounds__(256) void prep_w_kernel(
    const float* __restrict__ W, _Float16* __restrict__ WF) {
    int n = blockIdx.x * 256 + threadIdx.x;   // 32768
    int chunk = n >> 8;
    int et    = (n >> 6) & 3;
    int lane  = n & 63;
    int e  = et * 16 + (lane & 15);
    int k0 = chunk * 32 + (lane >> 4) * 8;
    const float* src = W + (size_t)e * DIM + k0;
    v8h h, l;
    #pragma unroll
    for (int j = 0; j < 8; ++j) {
        float w = src[j];
        _Float16 wh = (_Float16)w;
        h[j] = wh;
        l[j] = (_Float16)((w - (float)wh) * 2048.0f);
    }
    size_t base = (size_t)chunk * 4096 + (size_t)et * 512 + (size_t)lane * 8;
    *(v8h*)(WF + base)        = h;
    *(v8h*)(WF + base + 2048) = l;
}

// ---- helpers: all buffer names / indices compile-time --------------------
#define LOAD_A(Aa, Ab, cc) do {                                               \
    const float* ap_ = abase + (cc) * 32;                                     \
    Aa = *(const float4*)ap_;                                                 \
    Ab = *(const float4*)(ap_ + 4);                                           \
} while (0)

// load half-chunk (cc, half): 2 hi frags + 2 lo frags (e4 = half*2, half*2+1)
#define LOAD_BH(H0, H1, L0, L1, cc, half) do {                                \
    const _Float16* hp_ = wbH + (size_t)(cc) * 4096 + (half) * 1024;          \
    const _Float16* lp_ = wbL + (size_t)(cc) * 4096 + (half) * 1024;          \
    H0 = *(const v8h*)(hp_);                                                  \
    H1 = *(const v8h*)(hp_ + 512);                                            \
    L0 = *(const v8h*)(lp_);                                                  \
    L1 = *(const v8h*)(lp_ + 512);                                            \
} while (0)

#define CVT1(f, j) {                                                          \
    _Float16 h_ = (_Float16)(f);                                              \
    ah[j] = h_;                                                               \
    al[j] = (_Float16)(((f) - (float)h_) * 2048.0f);                          \
}
#define CVT(Aa, Ab) do {                                                      \
    CVT1(Aa.x, 0) CVT1(Aa.y, 1) CVT1(Aa.z, 2) CVT1(Aa.w, 3)                   \
    CVT1(Ab.x, 4) CVT1(Ab.y, 5) CVT1(Ab.z, 6) CVT1(Ab.w, 7)                   \
} while (0)

#define COMP_HALF(e0, H0, H1, L0, L1) do {                                    \
    acc1[e0]     = __builtin_amdgcn_mfma_f32_16x16x32_f16(ah, H0, acc1[e0], 0, 0, 0);     \
    acc1[e0 + 1] = __builtin_amdgcn_mfma_f32_16x16x32_f16(ah, H1, acc1[e0 + 1], 0, 0, 0); \
    acc2[e0]     = __builtin_amdgcn_mfma_f32_16x16x32_f16(al, H0, acc2[e0], 0, 0, 0);     \
    acc2[e0]     = __builtin_amdgcn_mfma_f32_16x16x32_f16(ah, L0, acc2[e0], 0, 0, 0);     \
    acc2[e0 + 1] = __builtin_amdgcn_mfma_f32_16x16x32_f16(al, H1, acc2[e0 + 1], 0, 0, 0); \
    acc2[e0 + 1] = __builtin_amdgcn_mfma_f32_16x16x32_f16(ah, L1, acc2[e0 + 1], 0, 0, 0); \
} while (0)

// full chunk: compute cc; issue B(cc+1) (needed soon) BEFORE A(cc+4) (needed
// late) so in-order vmcnt waits on B never force-drain the young A load.
#define CHUNK_FULL(AXa, AXb, cc) do {                                         \
    CVT(AXa, AXb);                                                            \
    COMP_HALF(0, B0a, B0b, B0c, B0d);                                         \
    LOAD_BH(B0a, B0b, B0c, B0d, (cc) + 1, 0);                                 \
    COMP_HALF(2, B1a, B1b, B1c, B1d);                                         \
    LOAD_BH(B1a, B1b, B1c, B1d, (cc) + 1, 1);                                 \
    __builtin_amdgcn_sched_barrier(0);                                        \
    LOAD_A(AXa, AXb, (cc) + 4);                                               \
} while (0)

#define CHUNK_NB(AXa, AXb, cc) do {  /* tail: B loads, no A */                \
    CVT(AXa, AXb);                                                            \
    COMP_HALF(0, B0a, B0b, B0c, B0d);                                         \
    LOAD_BH(B0a, B0b, B0c, B0d, (cc) + 1, 0);                                 \
    COMP_HALF(2, B1a, B1b, B1c, B1d);                                         \
    LOAD_BH(B1a, B1b, B1c, B1d, (cc) + 1, 1);                                 \
} while (0)

#define CHUNK_LAST(AXa, AXb) do {    /* last: no loads */                     \
    CVT(AXa, AXb);                                                            \
    COMP_HALF(0, B0a, B0b, B0c, B0d);                                         \
    COMP_HALF(2, B1a, B1b, B1c, B1d);                                         \
} while (0)

// ---------------------------------------------------------------------------
// Single-pass logits + top-2. 512 blocks x 512 thr (8 waves = K-eighths,
// 16 chunks of K=32 each -> 4 waves/SIMD). A from global depth-4; B from
// L2-hot WF as half-chunk ping-pong (issued before A in program order).
// ---------------------------------------------------------------------------
__global__ __launch_bounds__(512, 4) void topkgate_kernel(
    const float* __restrict__ x,
    const _Float16* __restrict__ WF,
    float* __restrict__ out) {

    __shared__ float red[8][16][65];      // padded: conflict-free epilogue writes

    const int tid  = threadIdx.x;
    const int wq   = tid >> 6;            // K-eighth (512 d)
    const int lane = tid & 63;
    const int tok0 = blockIdx.x * 16;
    const int art  = lane & 15;           // token row in tile
    const int akg  = lane >> 4;           // k-group
    const int chunk0 = wq * 16;

    const float*    abase = x   + (size_t)(tok0 + art) * DIM + chunk0 * 32 + akg * 8;
    const _Float16* wbH   = WF  + (size_t)chunk0 * 4096 + (size_t)lane * 8;
    const _Float16* wbL   = wbH + 2048;

    v4f acc1[4], acc2[4];
    #pragma unroll
    for (int e4 = 0; e4 < 4; ++e4) { acc1[e4] = (v4f)0.0f; acc2[e4] = (v4f)0.0f; }

    float4 A0a, A0b, A1a, A1b, A2a, A2b, A3a, A3b;
    v8h B0a, B0b, B0c, B0d, B1a, B1b, B1c, B1d;
    v8h ah, al;

    // prologue: B(0) first (needed first), then A(0..3)
    LOAD_BH(B0a, B0b, B0c, B0d, 0, 0);
    LOAD_BH(B1a, B1b, B1c, B1d, 0, 1);
    LOAD_A(A0a, A0b, 0);
    LOAD_A(A1a, A1b, 1);
    LOAD_A(A2a, A2b, 2);
    LOAD_A(A3a, A3b, 3);

    #pragma unroll 1
    for (int c = 0; c < 12; c += 4) {     // chunks 0..11 (A loads up to 15)
        CHUNK_FULL(A0a, A0b, c);
        CHUNK_FULL(A1a, A1b, c + 1);
        CHUNK_FULL(A2a, A2b, c + 2);
        CHUNK_FULL(A3a, A3b, c + 3);
    }
    CHUNK_NB(A0a, A0b, 12);               // B loads for 13..15
    CHUNK_NB(A1a, A1b, 13);
    CHUNK_NB(A2a, A2b, 14);
    CHUNK_LAST(A3a, A3b);                 // chunk 15

    // combine split terms -> red[wq][token][expert]
    // C/D layout: col(expert frag) = lane&15, row = (lane>>4)*4 + reg
    const float inv2048 = 1.0f / 2048.0f;
    #pragma unroll
    for (int e4 = 0; e4 < 4; ++e4) {
        #pragma unroll
        for (int r = 0; r < 4; ++r) {
            red[wq][akg * 4 + r][e4 * 16 + art] = acc1[e4][r] + acc2[e4][r] * inv2048;
        }
    }
    __syncthreads();

    // per-token top-2 + gates; wave wq handles tokens wq*2, wq*2+1
    #pragma unroll
    for (int tt = 0; tt < 2; ++tt) {
        int t = wq * 2 + tt;
        float v = red[0][t][lane] + red[1][t][lane]
                + red[2][t][lane] + red[3][t][lane]
                + red[4][t][lane] + red[5][t][lane]
                + red[6][t][lane] + red[7][t][lane];     // logit[t][lane]

        // argmax #1 (tie-break: smaller index, matching jax.lax.top_k)
        float bv = v; int bi = lane;
        #pragma unroll
        for (int off = 32; off >= 1; off >>= 1) {
            float ov = __shfl_xor(bv, off);
            int   oi = __shfl_xor(bi, off);
            if (ov > bv || (ov == bv && oi < bi)) { bv = ov; bi = oi; }
        }
        // argmax #2 (exclude bi)
        float v2 = (lane == bi) ? -FLT_MAX : v;
        float bv2 = v2; int bi2 = lane;
        #pragma unroll
        for (int off = 32; off >= 1; off >>= 1) {
            float ov = __shfl_xor(bv2, off);
            int   oi = __shfl_xor(bi2, off);
            if (ov > bv2 || (ov == bv2 && oi < bi2)) { bv2 = ov; bi2 = oi; }
        }

        if (lane == 0) {
            // top-2 renormalized softmax cancels: g0 = 1/(1+exp(l1-l0))
            float g0 = 1.0f / (1.0f + expf(bv2 - bv));
            int gt = tok0 + t;
            out[gt]              = (float)bi;
            out[TOKENS + gt]     = (float)bi2;
            out[2 * TOKENS + gt] = g0;
            out[3 * TOKENS + gt] = 1.0f - g0;
        }
    }
}

extern "C" void kernel_launch(void* const* d_in, const int* in_sizes, int n_in,
                              void* d_out, int out_size, void* d_ws, size_t ws_size,
                              hipStream_t stream) {
    const float* x = (const float*)d_in[0];   // [8192, 4096] fp32
    const float* W = (const float*)d_in[1];   // [64, 4096] fp32
    float* out     = (float*)d_out;           // [4 * 8192] fp32
    _Float16* WF   = (_Float16*)d_ws;         // 1 MB fragments

    prep_w_kernel<<<128, 256, 0, stream>>>(W, WF);
    topkgate_kernel<<<TOKENS / 16, 512, 0, stream>>>(x, WF, out);
}

// Round 8
// 41.077 us; speedup vs baseline: 64.0717x; 1.1303x over previous
//
#include <hip/hip_runtime.h>
#include <float.h>
#include <math.h>

#define TOKENS 8192
#define DIM    4096

typedef _Float16 v8h  __attribute__((ext_vector_type(8)));
typedef float    v4f  __attribute__((ext_vector_type(4)));

typedef __attribute__((address_space(3))) unsigned int lds_uint;
typedef const __attribute__((address_space(1))) unsigned int glob_uint;

__device__ __forceinline__ void stage16(const _Float16* g, _Float16* l) {
    // one instr: 64 lanes x 16 B -> LDS at (wave-uniform base + lane*16)
    __builtin_amdgcn_global_load_lds((glob_uint*)g, (lds_uint*)l, 16, 0, 0);
}

// ---------------------------------------------------------------------------
// Prep: fp16 hi/lo split B-fragments of W in d_ws (1 MB).
// WF[chunk(128)][term(2)][et(4)][lane(64)][8]:
//   B[k][n] with n = et*16 + (lane&15), k = chunk*32 + (lane>>4)*8 + j
// One chunk slab = 4096 halfs = 8 KB, contiguous.
// ---------------------------------------------------------------------------
__global__ __launch_bounds__(256) void prep_w_kernel(
    const float* __restrict__ W, _Float16* __restrict__ WF) {
    int n = blockIdx.x * 256 + threadIdx.x;   // 32768
    int chunk = n >> 8;
    int et    = (n >> 6) & 3;
    int lane  = n & 63;
    int e  = et * 16 + (lane & 15);
    int k0 = chunk * 32 + (lane >> 4) * 8;
    const float* src = W + (size_t)e * DIM + k0;
    v8h h, l;
    #pragma unroll
    for (int j = 0; j < 8; ++j) {
        float w = src[j];
        _Float16 wh = (_Float16)w;
        h[j] = wh;
        l[j] = (_Float16)((w - (float)wh) * 2048.0f);
    }
    size_t base = (size_t)chunk * 4096 + (size_t)et * 512 + (size_t)lane * 8;
    *(v8h*)(WF + base)        = h;
    *(v8h*)(WF + base + 2048) = l;
}

// ---- helpers (all names/indices compile-time) ------------------------------
#define LOAD_A(Aa, Ab, cc) do {                                               \
    const float* ap_ = abase + (cc) * 32;                                     \
    Aa = *(const float4*)ap_;                                                 \
    Ab = *(const float4*)(ap_ + 4);                                           \
} while (0)

// stage chunk cc's 8 KB slab into buf[BI]; each wave stages its 1 KB portion
#define STAGE(BI, cc) stage16(sbase + (size_t)(cc) * 4096, &buf[BI][wq * 512])

#define CVT1(f, j) {                                                          \
    _Float16 h_ = (_Float16)(f);                                              \
    ah[j] = h_;                                                               \
    al[j] = (_Float16)(((f) - (float)h_) * 2048.0f);                          \
}
#define CVT(Aa, Ab) do {                                                      \
    CVT1(Aa.x, 0) CVT1(Aa.y, 1) CVT1(Aa.z, 2) CVT1(Aa.w, 3)                   \
    CVT1(Ab.x, 4) CVT1(Ab.y, 5) CVT1(Ab.z, 6) CVT1(Ab.w, 7)                   \
} while (0)

#define MFMA16(a, b, c) __builtin_amdgcn_mfma_f32_16x16x32_f16(a, b, c, 0, 0, 0)

// compute chunk from buf[BI]: 8 conflict-free ds_read_b128 + 12 MFMA
#define COMPC(BI, Aa, Ab) do {                                                \
    CVT(Aa, Ab);                                                              \
    const _Float16* bp_ = &buf[BI][0] + (size_t)lane * 8;                     \
    v8h h0_ = *(const v8h*)(bp_);                                             \
    v8h h1_ = *(const v8h*)(bp_ + 512);                                       \
    v8h h2_ = *(const v8h*)(bp_ + 1024);                                      \
    v8h h3_ = *(const v8h*)(bp_ + 1536);                                      \
    v8h l0_ = *(const v8h*)(bp_ + 2048);                                      \
    v8h l1_ = *(const v8h*)(bp_ + 2560);                                      \
    v8h l2_ = *(const v8h*)(bp_ + 3072);                                      \
    v8h l3_ = *(const v8h*)(bp_ + 3584);                                      \
    acc1[0] = MFMA16(ah, h0_, acc1[0]);                                       \
    acc1[1] = MFMA16(ah, h1_, acc1[1]);                                       \
    acc1[2] = MFMA16(ah, h2_, acc1[2]);                                       \
    acc1[3] = MFMA16(ah, h3_, acc1[3]);                                       \
    acc2[0] = MFMA16(al, h0_, acc2[0]);  acc2[0] = MFMA16(ah, l0_, acc2[0]);  \
    acc2[1] = MFMA16(al, h1_, acc2[1]);  acc2[1] = MFMA16(ah, l1_, acc2[1]);  \
    acc2[2] = MFMA16(al, h2_, acc2[2]);  acc2[2] = MFMA16(ah, l2_, acc2[2]);  \
    acc2[3] = MFMA16(al, h3_, acc2[3]);  acc2[3] = MFMA16(ah, l3_, acc2[3]);  \
} while (0)

#define BARRIER_KEEP(n) do {                                                  \
    __builtin_amdgcn_sched_barrier(0);                                        \
    asm volatile("s_waitcnt vmcnt(" #n ")" ::: "memory");                     \
    __builtin_amdgcn_sched_barrier(0);                                        \
    __builtin_amdgcn_s_barrier();                                             \
    __builtin_amdgcn_sched_barrier(0);                                        \
} while (0)

// full iter: stage B(c+1) first, then A(c+2); end: drain stage, keep 2 A loads
#define ITER_FULL(c, ACa, ACb, ALa, ALb, BCUR, BNXT) do {                     \
    STAGE(BNXT, (c) + 1);                                                     \
    LOAD_A(ALa, ALb, (c) + 2);                                                \
    COMPC(BCUR, ACa, ACb);                                                    \
    BARRIER_KEEP(2);                                                          \
} while (0)

#define ITER_STAGE_ONLY(c, ACa, ACb, BCUR, BNXT) do {                         \
    STAGE(BNXT, (c) + 1);                                                     \
    COMPC(BCUR, ACa, ACb);                                                    \
    BARRIER_KEEP(0);                                                          \
} while (0)

// ---------------------------------------------------------------------------
// Pass 1: partial logits. 512 blocks x 512 thr (8 waves = 8 M-tiles of 16
// tokens -> 128 tokens/block). Block (tg, kg) covers K-slice kg (16 chunks).
// All 8 waves consume the SAME staged B chunk -> B global traffic 512->64 MB.
// ---------------------------------------------------------------------------
__global__ __launch_bounds__(512, 4) void logits_kernel(
    const float* __restrict__ x,
    const _Float16* __restrict__ WF,
    float* __restrict__ P) {

    __shared__ _Float16 buf[2][4096];     // 2 x 8 KB double-buffered B slab

    const int tid  = threadIdx.x;
    const int wq   = tid >> 6;            // wave = M-tile
    const int lane = tid & 63;
    const int kg   = (int)(blockIdx.x & 7);       // K-slice (512 d)
    const int tg   = (int)(blockIdx.x >> 3);      // token group (128 tokens)
    const int tok0 = tg * 128 + wq * 16;
    const int art  = lane & 15;           // token row within M-tile
    const int akg  = lane >> 4;           // k-group
    const int chunk0 = kg * 16;

    const float*    abase = x  + (size_t)(tok0 + art) * DIM + chunk0 * 32 + akg * 8;
    const _Float16* sbase = WF + (size_t)chunk0 * 4096 + (size_t)tid * 8;  // stage src

    v4f acc1[4], acc2[4];
    #pragma unroll
    for (int e4 = 0; e4 < 4; ++e4) { acc1[e4] = (v4f)0.0f; acc2[e4] = (v4f)0.0f; }

    float4 A0a, A0b, A1a, A1b, A2a, A2b;
    v8h ah, al;

    // prologue: stage chunk 0, A depth-2
    STAGE(0, 0);
    LOAD_A(A0a, A0b, 0);
    LOAD_A(A1a, A1b, 1);
    BARRIER_KEEP(4);                      // drain stage; keep the 4 A loads

    ITER_FULL(0,  A0a, A0b, A2a, A2b, 0, 1);
    ITER_FULL(1,  A1a, A1b, A0a, A0b, 1, 0);
    ITER_FULL(2,  A2a, A2b, A1a, A1b, 0, 1);
    ITER_FULL(3,  A0a, A0b, A2a, A2b, 1, 0);
    ITER_FULL(4,  A1a, A1b, A0a, A0b, 0, 1);
    ITER_FULL(5,  A2a, A2b, A1a, A1b, 1, 0);
    ITER_FULL(6,  A0a, A0b, A2a, A2b, 0, 1);
    ITER_FULL(7,  A1a, A1b, A0a, A0b, 1, 0);
    ITER_FULL(8,  A2a, A2b, A1a, A1b, 0, 1);
    ITER_FULL(9,  A0a, A0b, A2a, A2b, 1, 0);
    ITER_FULL(10, A1a, A1b, A0a, A0b, 0, 1);
    ITER_FULL(11, A2a, A2b, A1a, A1b, 1, 0);
    ITER_FULL(12, A0a, A0b, A2a, A2b, 0, 1);
    ITER_FULL(13, A1a, A1b, A0a, A0b, 1, 0);
    ITER_STAGE_ONLY(14, A2a, A2b, 0, 1);  // stage chunk 15; no more A loads
    COMPC(1, A0a, A0b);                   // chunk 15

    // write partial logits: C/D layout col=lane&15(expert), row=(lane>>4)*4+r
    const float inv2048 = 1.0f / 2048.0f;
    #pragma unroll
    for (int e4 = 0; e4 < 4; ++e4) {
        #pragma unroll
        for (int r = 0; r < 4; ++r) {
            float v = acc1[e4][r] + acc2[e4][r] * inv2048;
            P[((size_t)kg * TOKENS + tok0 + akg * 4 + r) * 64 + e4 * 16 + art] = v;
        }
    }
}

// ---------------------------------------------------------------------------
// Pass 2: logits = sum of 8 K-slice partials; top-2 + gates. 512 x 256.
// ---------------------------------------------------------------------------
__global__ __launch_bounds__(256) void reduce_topk_kernel(
    const float* __restrict__ P, float* __restrict__ out) {
    const int wq   = threadIdx.x >> 6;
    const int lane = threadIdx.x & 63;
    #pragma unroll
    for (int tt = 0; tt < 4; ++tt) {
        int gt = blockIdx.x * 16 + wq * 4 + tt;
        float v = 0.f;
        #pragma unroll
        for (int kg = 0; kg < 8; ++kg)
            v += P[((size_t)kg * TOKENS + gt) * 64 + lane];

        // argmax #1 (tie-break: smaller index, matching jax.lax.top_k)
        float bv = v; int bi = lane;
        #pragma unroll
        for (int off = 32; off >= 1; off >>= 1) {
            float ov = __shfl_xor(bv, off);
            int   oi = __shfl_xor(bi, off);
            if (ov > bv || (ov == bv && oi < bi)) { bv = ov; bi = oi; }
        }
        // argmax #2 (exclude bi)
        float v2 = (lane == bi) ? -FLT_MAX : v;
        float bv2 = v2; int bi2 = lane;
        #pragma unroll
        for (int off = 32; off >= 1; off >>= 1) {
            float ov = __shfl_xor(bv2, off);
            int   oi = __shfl_xor(bi2, off);
            if (ov > bv2 || (ov == bv2 && oi < bi2)) { bv2 = ov; bi2 = oi; }
        }

        if (lane == 0) {
            // top-2 renormalized softmax cancels: g0 = 1/(1+exp(l1-l0))
            float g0 = 1.0f / (1.0f + expf(bv2 - bv));
            out[gt]              = (float)bi;
            out[TOKENS + gt]     = (float)bi2;
            out[2 * TOKENS + gt] = g0;
            out[3 * TOKENS + gt] = 1.0f - g0;
        }
    }
}

extern "C" void kernel_launch(void* const* d_in, const int* in_sizes, int n_in,
                              void* d_out, int out_size, void* d_ws, size_t ws_size,
                              hipStream_t stream) {
    const float* x = (const float*)d_in[0];   // [8192, 4096] fp32
    const float* W = (const float*)d_in[1];   // [64, 4096] fp32
    float* out     = (float*)d_out;           // [4 * 8192] fp32
    _Float16* WF   = (_Float16*)d_ws;                     // 1 MB fragments
    float* P       = (float*)((char*)d_ws + (1 << 20));   // 16 MB partials

    prep_w_kernel<<<128, 256, 0, stream>>>(W, WF);
    logits_kernel<<<512, 512, 0, stream>>>(x, WF, P);
    reduce_topk_kernel<<<512, 256, 0, stream>>>(P, out);
}